// Round 1
// baseline (14358.116 us; speedup 1.0000x reference)
//
#include <hip/hip_runtime.h>
#include <hip/hip_bf16.h>
#include <cstdint>
#include <cstddef>

// ---------------------------------------------------------------------------
// 2-layer LSTM, T=512, B=64, IN=H=1024.
// Strategy: single persistent kernel, 256 blocks x 512 threads (guaranteed
// co-resident: capacity is 2 blocks/CU on 256 CUs), one device-wide barrier
// per timestep, layers pipelined at lag 1 (513 total steps).
// Weights are held in VGPRs as fp16 MFMA B-fragments for the whole kernel.
// ---------------------------------------------------------------------------

typedef _Float16 f16;
typedef _Float16 f16x8 __attribute__((ext_vector_type(8)));
typedef _Float16 f16x4 __attribute__((ext_vector_type(4)));
typedef float    f32x4 __attribute__((ext_vector_type(4)));

#define T_STEPS 512
#define BATCH   64
#define HID     1024
#define BH      (BATCH*HID)          /* 65536 elements */
#define WMAT    (4096*1024)          /* elements per weight matrix */
#define NBLK    256

// workspace layout (bytes)
static const size_t OFF_BAR = 0;                                   // 256 B
static const size_t OFF_X16 = 256;                                 // x in fp16
static const size_t OFF_W16 = OFF_X16 + (size_t)T_STEPS*BH*2;      // 4 weight mats fp16
static const size_t OFF_H1  = OFF_W16 + (size_t)4*WMAT*2;          // h1 double buffer
static const size_t OFF_H2  = OFF_H1  + (size_t)2*BH*2;            // h2 double buffer

// ---------------------------------------------------------------------------
// prep: fp32->fp16 conversion of x and the 4 weight matrices, h-state = 1.0
// init (reference uses h0 = ones, c0 = zeros), barrier counter = 0.
// ---------------------------------------------------------------------------
__global__ void prep_kernel(const float* __restrict__ x,
                            const float* __restrict__ wih0, const float* __restrict__ whh0,
                            const float* __restrict__ wih1, const float* __restrict__ whh1,
                            f16* __restrict__ x16, f16* __restrict__ w16,
                            f16* __restrict__ h1buf, f16* __restrict__ h2buf,
                            unsigned* __restrict__ bar)
{
    const size_t NX = (size_t)T_STEPS*BH/4;   // float4 units of x
    const size_t NW = (size_t)WMAT/4;         // float4 units per weight matrix
    const size_t NH = 32768;                  // f16x4 units of ones-init (2 buffers)
    size_t tid    = (size_t)blockIdx.x*blockDim.x + threadIdx.x;
    size_t stride = (size_t)gridDim.x*blockDim.x;
    size_t total  = NX + 4*NW + NH + 1;
    for (size_t i = tid; i < total; i += stride) {
        if (i < NX) {
            float4 v = ((const float4*)x)[i];
            f16x4 o = { (f16)v.x, (f16)v.y, (f16)v.z, (f16)v.w };
            ((f16x4*)x16)[i] = o;
        } else if (i < NX + 4*NW) {
            size_t j = i - NX;
            int mat = (int)(j / NW);
            size_t k = j % NW;
            const float* src = (mat==0) ? wih0 : (mat==1) ? whh0 : (mat==2) ? wih1 : whh1;
            float4 v = ((const float4*)src)[k];
            f16x4 o = { (f16)v.x, (f16)v.y, (f16)v.z, (f16)v.w };
            ((f16x4*)w16)[j] = o;
        } else if (i < NX + 4*NW + NH) {
            size_t j = i - NX - 4*NW;
            f16x4 one = { (f16)1.f, (f16)1.f, (f16)1.f, (f16)1.f };
            if (j < 16384) ((f16x4*)(h1buf + BH))[j] = one;         // h1buf[1] = ones
            else           ((f16x4*)(h2buf + BH))[j - 16384] = one; // h2buf[1] = ones
        } else {
            *bar = 0u;
        }
    }
}

__device__ __forceinline__ float sigm(float x) { return 1.f/(1.f + __expf(-x)); }
__device__ __forceinline__ float tanh_f(float x) {
    float e = __expf(-2.f*fabsf(x));      // e in (0,1], no overflow
    float r = (1.f - e)/(1.f + e);
    return x >= 0.f ? r : -r;
}

// ---------------------------------------------------------------------------
// persistent LSTM kernel.
//   block b: layer = b>>7, owns hidden units j0..j0+7 (j0 = (b&127)*8),
//            i.e. gate rows {j, 1024+j, 2048+j, 3072+j} packed as
//            n-tile0 = [i(8) | f(8)], n-tile1 = [g(8) | o(8)].
//   wave w (8 waves): kq = w>>1 (K-quarter of 2048: kq<2 -> w_ih/x-part,
//            kq>=2 -> w_hh/h-part), mh = w&1 (batch half: m-tiles 2mh,2mh+1).
//   -> disjoint (m,k) across waves: block reads each activation byte once.
// ---------------------------------------------------------------------------
__global__ __launch_bounds__(512, 2)
void lstm_kernel(const f16* __restrict__ x16, const f16* __restrict__ w16,
                 const float* __restrict__ b0, const float* __restrict__ b1,
                 f16* __restrict__ h1buf, f16* __restrict__ h2buf,
                 float* __restrict__ out, unsigned* __restrict__ bar)
{
    __shared__ float lds_part[4*2048];   // per-kq partial gate sums (tile-lane-major)
    __shared__ float lds_out[2048];      // reduced gates

    const int tid   = threadIdx.x;
    const int bid   = blockIdx.x;
    const int layer = bid >> 7;
    const int j0    = (bid & 127) << 3;
    const int wave  = tid >> 6, lane = tid & 63;
    const int kq    = wave >> 1, mh = wave & 1;
    const int l15   = lane & 15, l4 = lane >> 4;
    const int kp    = (kq & 1) * 512;    // k offset within the 1024-col matrix

    // ---- preload weight B-fragments: 2 n-tiles x 16 k-chunks = 128 VGPR ----
    // B[k][n] = W[n][k]; lane holds n = n0+(lane&15), k = k0+(lane>>4)*8+j
    const f16* wsrc = w16 + ((size_t)((layer<<1) + (kq>>1))) * WMAT; // ih then hh
    f16x8 Bf[2][16];
#pragma unroll
    for (int nt = 0; nt < 2; nt++) {
        int ln = (nt<<4) + l15;                       // local gate row 0..31
        int srcrow = (ln>>3)*1024 + j0 + (ln&7);      // gate-type*H + hidden idx
        const f16* rp = wsrc + (size_t)srcrow*1024 + kp + l4*8;
#pragma unroll
        for (int kc = 0; kc < 16; kc++)
            Bf[nt][kc] = *(const f16x8*)(rp + kc*32);
    }

    // ---- per-thread elementwise ownership: (batch bm, hidden u) ----
    const int bm = tid >> 3, u = tid & 7, j = j0 + u;
    const float* bias = layer ? b1 : b0;
    const float bi = bias[j], bff = bias[1024+j], bgg = bias[2048+j], boo = bias[3072+j];
    float c = 0.f;

    const int mrow0 = ((mh<<1) + 0)*16 + l15;  // A rows (batch) for this wave
    const int mrow1 = ((mh<<1) + 1)*16 + l15;
    // owner-read index pieces (tile-lane-major partial layout)
    const int li = ((bm>>2)&3) << 4;
    const int rr = bm & 3;
    const int tI = (bm>>4) << 1;               // tile for ln<16 (i,f); +1 for g,o

    for (int s = 0; s < T_STEPS + 1; s++) {
        const bool active = (layer == 0) ? (s < T_STEPS) : (s >= 1);
        if (active) {
            // activation sources for this step
            const f16* xpart = layer ? (h1buf + ((s-1)&1)*BH) : (x16 + (size_t)s*BH);
            const f16* hpart = layer ? (h2buf + (s&1)*BH)     : (h1buf + ((s-1)&1)*BH);
            const f16* asrc  = (kq < 2) ? xpart : hpart;
            const f16* a0 = asrc + (size_t)mrow0*1024 + kp + l4*8;
            const f16* a1 = asrc + (size_t)mrow1*1024 + kp + l4*8;

            f32x4 acc00 = {0.f,0.f,0.f,0.f}, acc01 = {0.f,0.f,0.f,0.f};
            f32x4 acc10 = {0.f,0.f,0.f,0.f}, acc11 = {0.f,0.f,0.f,0.f};
#pragma unroll
            for (int kc = 0; kc < 16; kc++) {
                f16x8 A0 = *(const f16x8*)(a0 + kc*32);
                f16x8 A1 = *(const f16x8*)(a1 + kc*32);
                acc00 = __builtin_amdgcn_mfma_f32_16x16x32_f16(A0, Bf[0][kc], acc00, 0,0,0);
                acc01 = __builtin_amdgcn_mfma_f32_16x16x32_f16(A0, Bf[1][kc], acc01, 0,0,0);
                acc10 = __builtin_amdgcn_mfma_f32_16x16x32_f16(A1, Bf[0][kc], acc10, 0,0,0);
                acc11 = __builtin_amdgcn_mfma_f32_16x16x32_f16(A1, Bf[1][kc], acc11, 0,0,0);
            }
            // partials -> LDS, tile-lane-major so the 4 acc regs are contiguous (b128)
            {
                const int base = kq*2048 + lane*4;
                *(f32x4*)&lds_part[base + (((mh<<1)+0)*2 + 0)*256] = acc00;
                *(f32x4*)&lds_part[base + (((mh<<1)+0)*2 + 1)*256] = acc01;
                *(f32x4*)&lds_part[base + (((mh<<1)+1)*2 + 0)*256] = acc10;
                *(f32x4*)&lds_part[base + (((mh<<1)+1)*2 + 1)*256] = acc11;
            }
            __syncthreads();
            // 4-way cross-wave reduction, layout-agnostic (contiguous f32x4)
            {
                f32x4 sum = *(const f32x4*)&lds_part[tid*4];
                sum += *(const f32x4*)&lds_part[2048 + tid*4];
                sum += *(const f32x4*)&lds_part[4096 + tid*4];
                sum += *(const f32x4*)&lds_part[6144 + tid*4];
                *(f32x4*)&lds_out[tid*4] = sum;
            }
            __syncthreads();
            // elementwise LSTM cell for (bm, j)
            {
                float gi = lds_out[(tI+0)*256 + (li +     u)*4 + rr] + bi;   // ln = u
                float gf = lds_out[(tI+0)*256 + (li + 8 + u)*4 + rr] + bff;  // ln = 8+u
                float gg = lds_out[(tI+1)*256 + (li +     u)*4 + rr] + bgg;  // ln = 16+u
                float go = lds_out[(tI+1)*256 + (li + 8 + u)*4 + rr] + boo;  // ln = 24+u
                float iv = sigm(gi), fv = sigm(gf), gv = tanh_f(gg), ov = sigm(go);
                c = fv*c + iv*gv;
                float h = ov * tanh_f(c);
                if (layer == 0) {
                    h1buf[(s&1)*BH + bm*1024 + j] = (f16)h;
                } else {
                    h2buf[((s-1)&1)*BH + bm*1024 + j] = (f16)h;
                    out[(size_t)(s-1)*BH + bm*1024 + j] = h;
                }
            }
        }
        // ---- device-wide step barrier (monotonic counter, all 256 blocks) ----
        __syncthreads();   // also drains this block's global stores (vmcnt before s_barrier)
        if (tid == 0) {
            __threadfence();                       // agent release: wbl2 so h is visible cross-XCD
            atomicAdd(bar, 1u);
            const unsigned tgt = (unsigned)NBLK * (unsigned)(s + 1);
            while (__hip_atomic_load(bar, __ATOMIC_RELAXED, __HIP_MEMORY_SCOPE_AGENT) < tgt)
                __builtin_amdgcn_s_sleep(4);       // relaxed polls: no cache-inv thrash
            __threadfence();                       // agent acquire: inv L1/L2 before reading new h
        }
        __syncthreads();
    }
}

extern "C" void kernel_launch(void* const* d_in, const int* in_sizes, int n_in,
                              void* d_out, int out_size, void* d_ws, size_t ws_size,
                              hipStream_t stream) {
    const float* x    = (const float*)d_in[0];
    const float* wih0 = (const float*)d_in[1];
    const float* whh0 = (const float*)d_in[2];
    const float* b0   = (const float*)d_in[3];
    const float* wih1 = (const float*)d_in[4];
    const float* whh1 = (const float*)d_in[5];
    const float* b1   = (const float*)d_in[6];
    float* out = (float*)d_out;

    char* ws = (char*)d_ws;
    unsigned* bar = (unsigned*)(ws + OFF_BAR);
    f16* x16   = (f16*)(ws + OFF_X16);
    f16* w16   = (f16*)(ws + OFF_W16);
    f16* h1buf = (f16*)(ws + OFF_H1);
    f16* h2buf = (f16*)(ws + OFF_H2);

    prep_kernel<<<2048, 256, 0, stream>>>(x, wih0, whh0, wih1, whh1,
                                          x16, w16, h1buf, h2buf, bar);
    lstm_kernel<<<NBLK, 512, 0, stream>>>(x16, w16, b0, b1,
                                          h1buf, h2buf, out, bar);
}

// Round 2
// 8733.775 us; speedup vs baseline: 1.6440x; 1.6440x over previous
//
#include <hip/hip_runtime.h>
#include <hip/hip_bf16.h>
#include <cstdint>
#include <cstddef>

// ---------------------------------------------------------------------------
// 2-layer LSTM, T=512, B=64, IN=H=1024. Persistent kernel, 256 blocks x 512
// threads (1 block/CU at ~200 VGPR), layers pipelined at lag 1.
// R2 changes vs R1:
//  - NO L2 fences in the loop: h1 is a 513-slab fresh-address history (never
//    reused => consumer L2 can't hold stale lines); stores are sc0/sc1
//    write-through via __hip_atomic_store; release = vmcnt drain only.
//  - Layer-1 recurrence reads d_out directly (fp32, monotonic addresses).
//  - Weights truly VGPR-resident: fp32->f16 convert at kernel start, pinned
//    with an asm barrier so the compiler cannot re-sink the loads (R1 bug:
//    VGPR_Count=92 proved frags were re-loaded from L2 every step).
//  - Tree barrier: 8 leaf counters (32 adds each) instead of 256 same-line
//    atomics; 8 lanes of wave0 poll the 8 leaves in parallel.
// ---------------------------------------------------------------------------

typedef _Float16 f16;
typedef _Float16 f16x8 __attribute__((ext_vector_type(8)));
typedef _Float16 f16x4 __attribute__((ext_vector_type(4)));
typedef float    f32x4 __attribute__((ext_vector_type(4)));

#define T_STEPS 512
#define BH      65536                 /* 64 batch x 1024 hidden */
#define NBLK    256

// workspace layout (bytes)
static const size_t LEAF_UINTS = (size_t)(T_STEPS + 2) * 8 * 16; // stride 64B per (step,group)
static const size_t OFF_LEAF   = 0;
static const size_t OFF_H1     = 0x60000;    // 384 KB; h1 history: 513 slabs * BH * 2B = 64.1 MB

// ---------------------------------------------------------------------------
// prep: zero leaf counters (harness poisons ws 0xAA), h1 slab 0 = ones
// (reference h0 = ones). Tiny now — no fp16 staging of x or weights.
// ---------------------------------------------------------------------------
__global__ void prep_kernel(f16* __restrict__ h1, unsigned* __restrict__ leaf)
{
    const int NONES = BH / 4;                 // f16x4 units = 16384
    const int NZ    = (int)(LEAF_UINTS / 4);  // uint4 units  = 16448
    int tid    = blockIdx.x * blockDim.x + threadIdx.x;
    int stride = gridDim.x * blockDim.x;
    f16x4 one = { (f16)1.f, (f16)1.f, (f16)1.f, (f16)1.f };
    uint4 z = { 0u, 0u, 0u, 0u };
    for (int i = tid; i < NONES + NZ; i += stride) {
        if (i < NONES) ((f16x4*)h1)[i] = one;
        else           ((uint4*)leaf)[i - NONES] = z;
    }
}

__device__ __forceinline__ float sigm(float x) { return 1.f/(1.f + __expf(-x)); }
__device__ __forceinline__ float tanh_f(float x) {
    float e = __expf(-2.f*fabsf(x));
    float r = (1.f - e)/(1.f + e);
    return x >= 0.f ? r : -r;
}
__device__ __forceinline__ f16x8 cvt8(float4 a, float4 b) {
    f16x8 r;
    r[0]=(f16)a.x; r[1]=(f16)a.y; r[2]=(f16)a.z; r[3]=(f16)a.w;
    r[4]=(f16)b.x; r[5]=(f16)b.y; r[6]=(f16)b.z; r[7]=(f16)b.w;
    return r;
}

// ---------------------------------------------------------------------------
// persistent LSTM kernel. Partition identical to R1 (correctness-verified):
//   block b: layer = b>>7, hidden units j0..j0+7; gate rows {j,1024+j,2048+j,
//   3072+j} as n-tile0=[i|f], n-tile1=[g|o].
//   wave w: kq = w>>1 (K-quarter of 2048), mh = w&1 (batch half).
// Step s: layer0 computes h1 token s (reads x[s] fp32 + h1 slab s);
//         layer1 computes out token s-1 (reads h1 slab s + out[s-2] fp32,
//         ones-frags at s==1). h1 slab t+1 holds token t; slab 0 = ones.
// ---------------------------------------------------------------------------
__global__ __launch_bounds__(512, 2)
void lstm_kernel(const float* __restrict__ x,
                 const float* __restrict__ wih0, const float* __restrict__ whh0,
                 const float* __restrict__ b0,
                 const float* __restrict__ wih1, const float* __restrict__ whh1,
                 const float* __restrict__ b1,
                 f16* __restrict__ h1, float* __restrict__ out,
                 unsigned* __restrict__ leaf)
{
    __shared__ float lds_part[4*2048];
    __shared__ float lds_out[2048];

    const int tid   = threadIdx.x;
    const int bid   = blockIdx.x;
    const int layer = bid >> 7;
    const int j0    = (bid & 127) << 3;
    const int wave  = tid >> 6, lane = tid & 63;
    const int kq    = wave >> 1, mh = wave & 1;
    const int l15   = lane & 15, l4 = lane >> 4;
    const int kp    = (kq & 1) * 512;
    const int grp   = bid >> 5;

    // ---- weight preload: fp32 global -> f16 B-fragments, pinned in VGPRs ----
    const float* wsrc = (layer == 0) ? (kq < 2 ? wih0 : whh0)
                                     : (kq < 2 ? wih1 : whh1);
    f16x8 Bf[2][16];
#pragma unroll
    for (int nt = 0; nt < 2; nt++) {
        int ln = (nt<<4) + l15;
        int srcrow = (ln>>3)*1024 + j0 + (ln&7);
        const float* rp = wsrc + (size_t)srcrow*1024 + kp + l4*8;
#pragma unroll
        for (int kc = 0; kc < 16; kc++) {
            float4 a = *(const float4*)(rp + kc*32);
            float4 b = *(const float4*)(rp + kc*32 + 4);
            Bf[nt][kc] = cvt8(a, b);
        }
    }
    // opaque pin: frags become asm outputs -> cannot be rematerialized as loads
#pragma unroll
    for (int nt = 0; nt < 2; nt++)
#pragma unroll
        for (int kc = 0; kc < 16; kc++)
            asm volatile("" : "+v"(Bf[nt][kc]));

    // ---- per-thread elementwise ownership (verbatim from R1) ----
    const int bm = tid >> 3, u = tid & 7, j = j0 + u;
    const float* bias = layer ? b1 : b0;
    const float bi = bias[j], bff = bias[1024+j], bgg = bias[2048+j], boo = bias[3072+j];
    float c = 0.f;
    const int mrow0 = ((mh<<1) + 0)*16 + l15;
    const int mrow1 = ((mh<<1) + 1)*16 + l15;
    const int li = ((bm>>2)&3) << 4;
    const int rr = bm & 3;
    const int tI = (bm>>4) << 1;

    for (int s = 0; s <= T_STEPS; s++) {
        // ---- wait for all 256 blocks to have finished step s-1 ----
        if (s > 0) {
            if (tid < 8) {
                const unsigned* p = leaf + ((size_t)(s-1)*8 + tid)*16;
                while (__hip_atomic_load(p, __ATOMIC_RELAXED, __HIP_MEMORY_SCOPE_AGENT) < 32u)
                    __builtin_amdgcn_s_sleep(1);
            }
            __syncthreads();
        }

        const bool active = (layer == 0) ? (s < T_STEPS) : (s >= 1);
        if (active) {
            // A-operand source for this wave this step
            int mode; const f16* s16 = nullptr; const float* s32 = nullptr;
            if (layer == 0) {
                if (kq < 2) { mode = 1; s32 = x + (size_t)s*BH; }       // x fp32
                else        { mode = 0; s16 = h1 + (size_t)s*BH; }      // h1 tok s-1
            } else {
                if (kq < 2)      { mode = 0; s16 = h1 + (size_t)s*BH; } // h1 tok s-1
                else if (s == 1) { mode = 2; }                          // h2 init ones
                else             { mode = 1; s32 = out + (size_t)(s-2)*BH; }
            }

            f32x4 acc00 = {0,0,0,0}, acc01 = {0,0,0,0};
            f32x4 acc10 = {0,0,0,0}, acc11 = {0,0,0,0};

            if (mode == 0) {
                const f16* a0 = s16 + (size_t)mrow0*1024 + kp + l4*8;
                const f16* a1 = s16 + (size_t)mrow1*1024 + kp + l4*8;
#pragma unroll
                for (int kc = 0; kc < 16; kc++) {
                    f16x8 A0 = *(const f16x8*)(a0 + kc*32);
                    f16x8 A1 = *(const f16x8*)(a1 + kc*32);
                    acc00 = __builtin_amdgcn_mfma_f32_16x16x32_f16(A0, Bf[0][kc], acc00, 0,0,0);
                    acc01 = __builtin_amdgcn_mfma_f32_16x16x32_f16(A0, Bf[1][kc], acc01, 0,0,0);
                    acc10 = __builtin_amdgcn_mfma_f32_16x16x32_f16(A1, Bf[0][kc], acc10, 0,0,0);
                    acc11 = __builtin_amdgcn_mfma_f32_16x16x32_f16(A1, Bf[1][kc], acc11, 0,0,0);
                }
            } else if (mode == 1) {
                const float* a0 = s32 + (size_t)mrow0*1024 + kp + l4*8;
                const float* a1 = s32 + (size_t)mrow1*1024 + kp + l4*8;
#pragma unroll
                for (int kc = 0; kc < 16; kc++) {
                    f16x8 A0 = cvt8(*(const float4*)(a0 + kc*32), *(const float4*)(a0 + kc*32 + 4));
                    f16x8 A1 = cvt8(*(const float4*)(a1 + kc*32), *(const float4*)(a1 + kc*32 + 4));
                    acc00 = __builtin_amdgcn_mfma_f32_16x16x32_f16(A0, Bf[0][kc], acc00, 0,0,0);
                    acc01 = __builtin_amdgcn_mfma_f32_16x16x32_f16(A0, Bf[1][kc], acc01, 0,0,0);
                    acc10 = __builtin_amdgcn_mfma_f32_16x16x32_f16(A1, Bf[0][kc], acc10, 0,0,0);
                    acc11 = __builtin_amdgcn_mfma_f32_16x16x32_f16(A1, Bf[1][kc], acc11, 0,0,0);
                }
            } else {
                f16x8 A1s;
#pragma unroll
                for (int e = 0; e < 8; e++) A1s[e] = (f16)1.f;
#pragma unroll
                for (int kc = 0; kc < 16; kc++) {
                    acc00 = __builtin_amdgcn_mfma_f32_16x16x32_f16(A1s, Bf[0][kc], acc00, 0,0,0);
                    acc01 = __builtin_amdgcn_mfma_f32_16x16x32_f16(A1s, Bf[1][kc], acc01, 0,0,0);
                    acc10 = __builtin_amdgcn_mfma_f32_16x16x32_f16(A1s, Bf[0][kc], acc10, 0,0,0);
                    acc11 = __builtin_amdgcn_mfma_f32_16x16x32_f16(A1s, Bf[1][kc], acc11, 0,0,0);
                }
            }

            // partials -> LDS (tile-lane-major, b128), 4-way reduce (verbatim R1)
            {
                const int base = kq*2048 + lane*4;
                *(f32x4*)&lds_part[base + (((mh<<1)+0)*2 + 0)*256] = acc00;
                *(f32x4*)&lds_part[base + (((mh<<1)+0)*2 + 1)*256] = acc01;
                *(f32x4*)&lds_part[base + (((mh<<1)+1)*2 + 0)*256] = acc10;
                *(f32x4*)&lds_part[base + (((mh<<1)+1)*2 + 1)*256] = acc11;
            }
            __syncthreads();
            {
                f32x4 sum = *(const f32x4*)&lds_part[tid*4];
                sum += *(const f32x4*)&lds_part[2048 + tid*4];
                sum += *(const f32x4*)&lds_part[4096 + tid*4];
                sum += *(const f32x4*)&lds_part[6144 + tid*4];
                *(f32x4*)&lds_out[tid*4] = sum;
            }
            __syncthreads();
            // elementwise LSTM cell for (bm, j)
            {
                float gi = lds_out[(tI+0)*256 + (li +     u)*4 + rr] + bi;
                float gf = lds_out[(tI+0)*256 + (li + 8 + u)*4 + rr] + bff;
                float gg = lds_out[(tI+1)*256 + (li +     u)*4 + rr] + bgg;
                float go = lds_out[(tI+1)*256 + (li + 8 + u)*4 + rr] + boo;
                float iv = sigm(gi), fv = sigm(gf), gv = tanh_f(gg), ov = sigm(go);
                c = fv*c + iv*gv;
                float h = ov * tanh_f(c);
                if (layer == 0) {
                    f16 hv = (f16)h;
                    short hs = __builtin_bit_cast(short, hv);
                    __hip_atomic_store((short*)(h1 + (size_t)(s+1)*BH + bm*1024 + j), hs,
                                       __ATOMIC_RELAXED, __HIP_MEMORY_SCOPE_AGENT);
                } else {
                    __hip_atomic_store(out + (size_t)(s-1)*BH + bm*1024 + j, h,
                                       __ATOMIC_RELAXED, __HIP_MEMORY_SCOPE_AGENT);
                }
            }
        }

        // ---- publish step s: drain write-through stores, then leaf add ----
        __builtin_amdgcn_s_waitcnt(0);   // vmcnt(0): sc1 stores globally visible
        __syncthreads();
        if (tid == 0)
            atomicAdd(leaf + ((size_t)s*8 + grp)*16, 1u);
    }
}

extern "C" void kernel_launch(void* const* d_in, const int* in_sizes, int n_in,
                              void* d_out, int out_size, void* d_ws, size_t ws_size,
                              hipStream_t stream) {
    const float* x    = (const float*)d_in[0];
    const float* wih0 = (const float*)d_in[1];
    const float* whh0 = (const float*)d_in[2];
    const float* b0   = (const float*)d_in[3];
    const float* wih1 = (const float*)d_in[4];
    const float* whh1 = (const float*)d_in[5];
    const float* b1   = (const float*)d_in[6];
    float* out = (float*)d_out;

    char* ws = (char*)d_ws;
    unsigned* leaf = (unsigned*)(ws + OFF_LEAF);
    f16* h1        = (f16*)(ws + OFF_H1);

    prep_kernel<<<256, 256, 0, stream>>>(h1, leaf);
    lstm_kernel<<<NBLK, 512, 0, stream>>>(x, wih0, whh0, b0, wih1, whh1, b1,
                                          h1, out, leaf);
}

// Round 3
// 7142.876 us; speedup vs baseline: 2.0101x; 1.2227x over previous
//
#include <hip/hip_runtime.h>
#include <hip/hip_bf16.h>
#include <cstdint>
#include <cstddef>

// ---------------------------------------------------------------------------
// 2-layer LSTM, T=512, B=64, IN=H=1024. Persistent kernel, 256 blocks x 512
// threads, layers pipelined at lag 1.
// R3 changes vs R2 (data path identical to R2 — proven absmax 1.95e-3):
//  - Barrier: NO atomics/RMWs in the loop. Per-block monotonic epoch flag
//    (one 64B line each, plain sc1 store) + all-gather polling (thread tid
//    polls flag[tid] — read-only, spread over 128/256 L3 lines).
//    R2's counter barrier serialized 256 RMWs into 8 contended L3 lines
//    (~16k cyc/step — the dominant cost: VALUBusy 6.7% showed 94% waiting).
//  - Split by layer: L0 blocks wait only on the 128 L0 flags (L0 never reads
//    L1 data; h1 is a never-overwritten history, so L0 can run ahead
//    unboundedly and pre-warms L3 for L1). L1 waits on all 256 flags, but
//    the L0 half is always already satisfied -> two independent 128-chains.
// ---------------------------------------------------------------------------

typedef _Float16 f16;
typedef _Float16 f16x8 __attribute__((ext_vector_type(8)));
typedef _Float16 f16x4 __attribute__((ext_vector_type(4)));
typedef float    f32x4 __attribute__((ext_vector_type(4)));

#define T_STEPS 512
#define BH      65536                 /* 64 batch x 1024 hidden */
#define NBLK    256

// workspace layout (bytes)
static const size_t OFF_FLAG = 0;            // 256 blocks * 64 B = 16 KB
static const size_t OFF_H1   = 0x60000;      // h1 history: 513 slabs * BH * 2B = 64.1 MB

// ---------------------------------------------------------------------------
// prep: zero flags (harness poisons ws 0xAA), h1 slab 0 = ones (ref h0=ones).
// ---------------------------------------------------------------------------
__global__ void prep_kernel(f16* __restrict__ h1, unsigned* __restrict__ flags)
{
    const int NONES = BH / 4;                 // f16x4 units = 16384
    const int NZ    = NBLK * 16 / 4;          // uint4 units = 1024
    int tid    = blockIdx.x * blockDim.x + threadIdx.x;
    int stride = gridDim.x * blockDim.x;
    f16x4 one = { (f16)1.f, (f16)1.f, (f16)1.f, (f16)1.f };
    uint4 z = { 0u, 0u, 0u, 0u };
    for (int i = tid; i < NONES + NZ; i += stride) {
        if (i < NONES) ((f16x4*)h1)[i] = one;
        else           ((uint4*)flags)[i - NONES] = z;
    }
}

__device__ __forceinline__ float sigm(float x) { return 1.f/(1.f + __expf(-x)); }
__device__ __forceinline__ float tanh_f(float x) {
    float e = __expf(-2.f*fabsf(x));
    float r = (1.f - e)/(1.f + e);
    return x >= 0.f ? r : -r;
}
__device__ __forceinline__ f16x8 cvt8(float4 a, float4 b) {
    f16x8 r;
    r[0]=(f16)a.x; r[1]=(f16)a.y; r[2]=(f16)a.z; r[3]=(f16)a.w;
    r[4]=(f16)b.x; r[5]=(f16)b.y; r[6]=(f16)b.z; r[7]=(f16)b.w;
    return r;
}

// ---------------------------------------------------------------------------
// persistent LSTM kernel. Partition (verbatim R1/R2, correctness-verified):
//   block b: layer = b>>7, hidden units j0..j0+7; gate rows {j,1024+j,2048+j,
//   3072+j} as n-tile0=[i|f], n-tile1=[g|o].
//   wave w: kq = w>>1 (K-quarter of 2048), mh = w&1 (batch half).
// Step s: layer0 computes h1 token s (reads x[s] fp32 + h1 slab s);
//         layer1 computes out token s-1 (reads h1 slab s + out[s-2] fp32,
//         ones-frags at s==1). h1 slab t+1 holds token t; slab 0 = ones.
// ---------------------------------------------------------------------------
__global__ __launch_bounds__(512, 2)
void lstm_kernel(const float* __restrict__ x,
                 const float* __restrict__ wih0, const float* __restrict__ whh0,
                 const float* __restrict__ b0,
                 const float* __restrict__ wih1, const float* __restrict__ whh1,
                 const float* __restrict__ b1,
                 f16* __restrict__ h1, float* __restrict__ out,
                 unsigned* __restrict__ flags)
{
    __shared__ float lds_part[4*2048];
    __shared__ float lds_out[2048];

    const int tid   = threadIdx.x;
    const int bid   = blockIdx.x;
    const int layer = bid >> 7;
    const int j0    = (bid & 127) << 3;
    const int wave  = tid >> 6, lane = tid & 63;
    const int kq    = wave >> 1, mh = wave & 1;
    const int l15   = lane & 15, l4 = lane >> 4;
    const int kp    = (kq & 1) * 512;
    const int nflag = layer ? NBLK : 128;    // L0 waits only on L0 peers

    // ---- weight preload: fp32 global -> f16 B-fragments, pinned in VGPRs ----
    const float* wsrc = (layer == 0) ? (kq < 2 ? wih0 : whh0)
                                     : (kq < 2 ? wih1 : whh1);
    f16x8 Bf[2][16];
#pragma unroll
    for (int nt = 0; nt < 2; nt++) {
        int ln = (nt<<4) + l15;
        int srcrow = (ln>>3)*1024 + j0 + (ln&7);
        const float* rp = wsrc + (size_t)srcrow*1024 + kp + l4*8;
#pragma unroll
        for (int kc = 0; kc < 16; kc++) {
            float4 a = *(const float4*)(rp + kc*32);
            float4 b = *(const float4*)(rp + kc*32 + 4);
            Bf[nt][kc] = cvt8(a, b);
        }
    }
    // opaque pin: frags become asm outputs -> cannot be re-sunk into the loop
#pragma unroll
    for (int nt = 0; nt < 2; nt++)
#pragma unroll
        for (int kc = 0; kc < 16; kc++)
            asm volatile("" : "+v"(Bf[nt][kc]));

    // ---- per-thread elementwise ownership (verbatim R1/R2) ----
    const int bm = tid >> 3, u = tid & 7, j = j0 + u;
    const float* bias = layer ? b1 : b0;
    const float bi = bias[j], bff = bias[1024+j], bgg = bias[2048+j], boo = bias[3072+j];
    float c = 0.f;
    const int mrow0 = ((mh<<1) + 0)*16 + l15;
    const int mrow1 = ((mh<<1) + 1)*16 + l15;
    const int li = ((bm>>2)&3) << 4;
    const int rr = bm & 3;
    const int tI = (bm>>4) << 1;

    for (int s = 0; s <= T_STEPS; s++) {
        // ---- wait: all needed peers have published step s-1 (flag >= s) ----
        if (s > 0) {
            if (tid < nflag) {
                const unsigned* p = flags + (size_t)tid*16;
                while (__hip_atomic_load(p, __ATOMIC_RELAXED, __HIP_MEMORY_SCOPE_AGENT) < (unsigned)s)
                    __builtin_amdgcn_s_sleep(2);
            }
            __syncthreads();
        }

        const bool active = (layer == 0) ? (s < T_STEPS) : (s >= 1);
        if (active) {
            // A-operand source for this wave this step
            int mode; const f16* s16 = nullptr; const float* s32 = nullptr;
            if (layer == 0) {
                if (kq < 2) { mode = 1; s32 = x + (size_t)s*BH; }       // x fp32
                else        { mode = 0; s16 = h1 + (size_t)s*BH; }      // h1 tok s-1
            } else {
                if (kq < 2)      { mode = 0; s16 = h1 + (size_t)s*BH; } // h1 tok s-1
                else if (s == 1) { mode = 2; }                          // h2 init ones
                else             { mode = 1; s32 = out + (size_t)(s-2)*BH; }
            }

            f32x4 acc00 = {0,0,0,0}, acc01 = {0,0,0,0};
            f32x4 acc10 = {0,0,0,0}, acc11 = {0,0,0,0};

            if (mode == 0) {
                const f16* a0 = s16 + (size_t)mrow0*1024 + kp + l4*8;
                const f16* a1 = s16 + (size_t)mrow1*1024 + kp + l4*8;
#pragma unroll
                for (int kc = 0; kc < 16; kc++) {
                    f16x8 A0 = *(const f16x8*)(a0 + kc*32);
                    f16x8 A1 = *(const f16x8*)(a1 + kc*32);
                    acc00 = __builtin_amdgcn_mfma_f32_16x16x32_f16(A0, Bf[0][kc], acc00, 0,0,0);
                    acc01 = __builtin_amdgcn_mfma_f32_16x16x32_f16(A0, Bf[1][kc], acc01, 0,0,0);
                    acc10 = __builtin_amdgcn_mfma_f32_16x16x32_f16(A1, Bf[0][kc], acc10, 0,0,0);
                    acc11 = __builtin_amdgcn_mfma_f32_16x16x32_f16(A1, Bf[1][kc], acc11, 0,0,0);
                }
            } else if (mode == 1) {
                const float* a0 = s32 + (size_t)mrow0*1024 + kp + l4*8;
                const float* a1 = s32 + (size_t)mrow1*1024 + kp + l4*8;
#pragma unroll
                for (int kc = 0; kc < 16; kc++) {
                    f16x8 A0 = cvt8(*(const float4*)(a0 + kc*32), *(const float4*)(a0 + kc*32 + 4));
                    f16x8 A1 = cvt8(*(const float4*)(a1 + kc*32), *(const float4*)(a1 + kc*32 + 4));
                    acc00 = __builtin_amdgcn_mfma_f32_16x16x32_f16(A0, Bf[0][kc], acc00, 0,0,0);
                    acc01 = __builtin_amdgcn_mfma_f32_16x16x32_f16(A0, Bf[1][kc], acc01, 0,0,0);
                    acc10 = __builtin_amdgcn_mfma_f32_16x16x32_f16(A1, Bf[0][kc], acc10, 0,0,0);
                    acc11 = __builtin_amdgcn_mfma_f32_16x16x32_f16(A1, Bf[1][kc], acc11, 0,0,0);
                }
            } else {
                f16x8 A1s;
#pragma unroll
                for (int e = 0; e < 8; e++) A1s[e] = (f16)1.f;
#pragma unroll
                for (int kc = 0; kc < 16; kc++) {
                    acc00 = __builtin_amdgcn_mfma_f32_16x16x32_f16(A1s, Bf[0][kc], acc00, 0,0,0);
                    acc01 = __builtin_amdgcn_mfma_f32_16x16x32_f16(A1s, Bf[1][kc], acc01, 0,0,0);
                    acc10 = __builtin_amdgcn_mfma_f32_16x16x32_f16(A1s, Bf[0][kc], acc10, 0,0,0);
                    acc11 = __builtin_amdgcn_mfma_f32_16x16x32_f16(A1s, Bf[1][kc], acc11, 0,0,0);
                }
            }

            // partials -> LDS (tile-lane-major, b128), 4-way reduce (verbatim)
            {
                const int base = kq*2048 + lane*4;
                *(f32x4*)&lds_part[base + (((mh<<1)+0)*2 + 0)*256] = acc00;
                *(f32x4*)&lds_part[base + (((mh<<1)+0)*2 + 1)*256] = acc01;
                *(f32x4*)&lds_part[base + (((mh<<1)+1)*2 + 0)*256] = acc10;
                *(f32x4*)&lds_part[base + (((mh<<1)+1)*2 + 1)*256] = acc11;
            }
            __syncthreads();
            {
                f32x4 sum = *(const f32x4*)&lds_part[tid*4];
                sum += *(const f32x4*)&lds_part[2048 + tid*4];
                sum += *(const f32x4*)&lds_part[4096 + tid*4];
                sum += *(const f32x4*)&lds_part[6144 + tid*4];
                *(f32x4*)&lds_out[tid*4] = sum;
            }
            __syncthreads();
            // elementwise LSTM cell for (bm, j)
            {
                float gi = lds_out[(tI+0)*256 + (li +     u)*4 + rr] + bi;
                float gf = lds_out[(tI+0)*256 + (li + 8 + u)*4 + rr] + bff;
                float gg = lds_out[(tI+1)*256 + (li +     u)*4 + rr] + bgg;
                float go = lds_out[(tI+1)*256 + (li + 8 + u)*4 + rr] + boo;
                float iv = sigm(gi), fv = sigm(gf), gv = tanh_f(gg), ov = sigm(go);
                c = fv*c + iv*gv;
                float h = ov * tanh_f(c);
                if (layer == 0) {
                    f16 hv = (f16)h;
                    short hs = __builtin_bit_cast(short, hv);
                    __hip_atomic_store((short*)(h1 + (size_t)(s+1)*BH + bm*1024 + j), hs,
                                       __ATOMIC_RELAXED, __HIP_MEMORY_SCOPE_AGENT);
                } else {
                    __hip_atomic_store(out + (size_t)(s-1)*BH + bm*1024 + j, h,
                                       __ATOMIC_RELAXED, __HIP_MEMORY_SCOPE_AGENT);
                }
            }
        }

        // ---- publish step s: drain write-through stores, then flag store ----
        __builtin_amdgcn_s_waitcnt(0);   // vmcnt(0): sc1 stores globally visible
        __syncthreads();                 // all threads of the block have drained
        if (tid == 0)
            __hip_atomic_store(flags + (size_t)bid*16, (unsigned)(s + 1),
                               __ATOMIC_RELAXED, __HIP_MEMORY_SCOPE_AGENT);
    }
}

extern "C" void kernel_launch(void* const* d_in, const int* in_sizes, int n_in,
                              void* d_out, int out_size, void* d_ws, size_t ws_size,
                              hipStream_t stream) {
    const float* x    = (const float*)d_in[0];
    const float* wih0 = (const float*)d_in[1];
    const float* whh0 = (const float*)d_in[2];
    const float* b0   = (const float*)d_in[3];
    const float* wih1 = (const float*)d_in[4];
    const float* whh1 = (const float*)d_in[5];
    const float* b1   = (const float*)d_in[6];
    float* out = (float*)d_out;

    char* ws = (char*)d_ws;
    unsigned* flags = (unsigned*)(ws + OFF_FLAG);
    f16* h1         = (f16*)(ws + OFF_H1);

    prep_kernel<<<256, 256, 0, stream>>>(h1, flags);
    lstm_kernel<<<NBLK, 512, 0, stream>>>(x, wih0, whh0, b0, wih1, whh1, b1,
                                          h1, out, flags);
}

// Round 4
// 7025.304 us; speedup vs baseline: 2.0438x; 1.0167x over previous
//
#include <hip/hip_runtime.h>
#include <hip/hip_bf16.h>
#include <cstdint>
#include <cstddef>

// ---------------------------------------------------------------------------
// 2-layer LSTM, T=512, B=64, IN=H=1024. Persistent kernel, 256 blocks x 512
// threads, layers pipelined at lag 1. Data path verbatim R3.
// R4 changes (theory: R3's hop was paced by STALE flag lines in the
// non-coherent consumer L2 — FETCH_SIZE shows polls generated no L2-miss
// traffic, so detection waited on capacity eviction, ~14 us/step):
//  - Sync path forced to bypass L2 with inline asm (sc1 on poll loads and
//    flag stores). Detection = L3 round trip, not an eviction lottery.
//  - Flags packed at 4-B stride (8 lines total); ONE wave polls all 256
//    flags via per-lane dwordx4; s_sleep(8) between failed polls.
//  - h1 history in block-major layout: producer writes are full-line
//    single-writer (1 line/wave), consumer A-reads contiguous 256-B runs.
// ---------------------------------------------------------------------------

typedef _Float16 f16;
typedef _Float16 f16x8 __attribute__((ext_vector_type(8)));
typedef _Float16 f16x4 __attribute__((ext_vector_type(4)));
typedef float    f32x4 __attribute__((ext_vector_type(4)));

#define T_STEPS 512
#define BH      65536                 /* 64 batch x 1024 hidden */
#define NBLK    256

// workspace layout (bytes)
static const size_t OFF_FLAG = 0;            // 256 x 4 B packed flags (8 lines)
static const size_t OFF_H1   = 0x60000;      // h1 history: 513 slabs * BH * 2B = 64.1 MB
// h1 slab layout is BLOCK-MAJOR: slab*65536 + jblk*512 + (bm*8 + u), f16.

// ---------------------------------------------------------------------------
__global__ void prep_kernel(f16* __restrict__ h1, unsigned* __restrict__ flags)
{
    const int NONES = BH / 4;                 // f16x4 units = 16384 (slab 0 = ones)
    const int NZ    = NBLK / 4;               // uint4 units = 64
    int tid    = blockIdx.x * blockDim.x + threadIdx.x;
    int stride = gridDim.x * blockDim.x;
    f16x4 one = { (f16)1.f, (f16)1.f, (f16)1.f, (f16)1.f };
    uint4 z = { 0u, 0u, 0u, 0u };
    for (int i = tid; i < NONES + NZ; i += stride) {
        if (i < NONES) ((f16x4*)h1)[i] = one;
        else           ((uint4*)flags)[i - NONES] = z;
    }
}

__device__ __forceinline__ float sigm(float x) { return 1.f/(1.f + __expf(-x)); }
__device__ __forceinline__ float tanh_f(float x) {
    float e = __expf(-2.f*fabsf(x));
    float r = (1.f - e)/(1.f + e);
    return x >= 0.f ? r : -r;
}
__device__ __forceinline__ f16x8 cvt8(float4 a, float4 b) {
    f16x8 r;
    r[0]=(f16)a.x; r[1]=(f16)a.y; r[2]=(f16)a.z; r[3]=(f16)a.w;
    r[4]=(f16)b.x; r[5]=(f16)b.y; r[6]=(f16)b.z; r[7]=(f16)b.w;
    return r;
}

// L2-bypass (device-scope) poll load: 16 B = 4 flags per lane.
__device__ __forceinline__ uint4 poll_load(const unsigned* p) {
    uint4 r;
    asm volatile("global_load_dwordx4 %0, %1, off sc1\n\ts_waitcnt vmcnt(0)"
                 : "=v"(r) : "v"(p) : "memory");
    return r;
}
// L2-bypass (device-scope) flag publish.
__device__ __forceinline__ void flag_store(unsigned* p, unsigned v) {
    asm volatile("global_store_dword %0, %1, off sc1" :: "v"(p), "v"(v) : "memory");
}

// ---------------------------------------------------------------------------
// persistent LSTM kernel. Partition (verbatim R1-R3, correctness-verified):
//   block b: layer = b>>7, hidden units j0..j0+7; gate rows {j,1024+j,2048+j,
//   3072+j} as n-tile0=[i|f], n-tile1=[g|o].
//   wave w: kq = w>>1 (K-quarter of 2048), mh = w&1 (batch half).
// Step s: layer0 computes h1 token s (reads x[s] fp32 + h1 slab s);
//         layer1 computes out token s-1 (reads h1 slab s + out[s-2] fp32,
//         ones-frags at s==1). h1 slab t+1 holds token t; slab 0 = ones.
// ---------------------------------------------------------------------------
__global__ __launch_bounds__(512, 2)
void lstm_kernel(const float* __restrict__ x,
                 const float* __restrict__ wih0, const float* __restrict__ whh0,
                 const float* __restrict__ b0,
                 const float* __restrict__ wih1, const float* __restrict__ whh1,
                 const float* __restrict__ b1,
                 f16* __restrict__ h1, float* __restrict__ out,
                 unsigned* __restrict__ flags)
{
    __shared__ float lds_part[4*2048];
    __shared__ float lds_out[2048];

    const int tid   = threadIdx.x;
    const int bid   = blockIdx.x;
    const int layer = bid >> 7;
    const int j0    = (bid & 127) << 3;
    const int wave  = tid >> 6, lane = tid & 63;
    const int kq    = wave >> 1, mh = wave & 1;
    const int l15   = lane & 15, l4 = lane >> 4;
    const int kp    = (kq & 1) * 512;
    const int pollN = layer ? 64 : 32;       // lanes polling (4 flags each)

    // ---- weight preload: fp32 global -> f16 B-fragments, pinned in VGPRs ----
    const float* wsrc = (layer == 0) ? (kq < 2 ? wih0 : whh0)
                                     : (kq < 2 ? wih1 : whh1);
    f16x8 Bf[2][16];
#pragma unroll
    for (int nt = 0; nt < 2; nt++) {
        int ln = (nt<<4) + l15;
        int srcrow = (ln>>3)*1024 + j0 + (ln&7);
        const float* rp = wsrc + (size_t)srcrow*1024 + kp + l4*8;
#pragma unroll
        for (int kc = 0; kc < 16; kc++) {
            float4 a = *(const float4*)(rp + kc*32);
            float4 b = *(const float4*)(rp + kc*32 + 4);
            Bf[nt][kc] = cvt8(a, b);
        }
    }
#pragma unroll
    for (int nt = 0; nt < 2; nt++)
#pragma unroll
        for (int kc = 0; kc < 16; kc++)
            asm volatile("" : "+v"(Bf[nt][kc]));

    // ---- per-thread elementwise ownership (verbatim R1-R3) ----
    const int bm = tid >> 3, u = tid & 7, j = j0 + u;
    const float* bias = layer ? b1 : b0;
    const float bi = bias[j], bff = bias[1024+j], bgg = bias[2048+j], boo = bias[3072+j];
    float c = 0.f;
    const int mrow0 = ((mh<<1) + 0)*16 + l15;
    const int mrow1 = ((mh<<1) + 1)*16 + l15;
    const int li = ((bm>>2)&3) << 4;
    const int rr = bm & 3;
    const int tI = (bm>>4) << 1;
    // block-major h1 A-read base offsets (region = 512 f16, 4 regions per kc)
    const int h1reg = (kq & 1) * 64 + l4;    // region index base for this lane

    for (int s = 0; s <= T_STEPS; s++) {
        // ---- wait: all needed peers have published step s-1 (flag >= s) ----
        if (s > 0) {
            if (tid < pollN) {
                const unsigned* p = flags + tid*4;
                for (;;) {
                    uint4 v = poll_load(p);
                    unsigned mn = v.x < v.y ? v.x : v.y;
                    unsigned mn2 = v.z < v.w ? v.z : v.w;
                    if ((mn < mn2 ? mn : mn2) >= (unsigned)s) break;
                    __builtin_amdgcn_s_sleep(8);
                }
            }
            __syncthreads();
        }

        const bool active = (layer == 0) ? (s < T_STEPS) : (s >= 1);
        if (active) {
            // A-operand source for this wave this step
            int mode; const f16* s16 = nullptr; const float* s32 = nullptr;
            if (layer == 0) {
                if (kq < 2) { mode = 1; s32 = x + (size_t)s*BH; }       // x fp32
                else        { mode = 0; s16 = h1 + (size_t)s*BH; }      // h1 tok s-1
            } else {
                if (kq < 2)      { mode = 0; s16 = h1 + (size_t)s*BH; } // h1 tok s-1
                else if (s == 1) { mode = 2; }                          // h2 init ones
                else             { mode = 1; s32 = out + (size_t)(s-2)*BH; }
            }

            f32x4 acc00 = {0,0,0,0}, acc01 = {0,0,0,0};
            f32x4 acc10 = {0,0,0,0}, acc11 = {0,0,0,0};

            if (mode == 0) {
                // block-major slab: addr = region*512 + mrow*8 ; region = h1reg + 4*kc
                const f16* a0 = s16 + (size_t)h1reg*512 + mrow0*8;
                const f16* a1 = s16 + (size_t)h1reg*512 + mrow1*8;
#pragma unroll
                for (int kc = 0; kc < 16; kc++) {
                    f16x8 A0 = *(const f16x8*)(a0 + kc*2048);
                    f16x8 A1 = *(const f16x8*)(a1 + kc*2048);
                    acc00 = __builtin_amdgcn_mfma_f32_16x16x32_f16(A0, Bf[0][kc], acc00, 0,0,0);
                    acc01 = __builtin_amdgcn_mfma_f32_16x16x32_f16(A0, Bf[1][kc], acc01, 0,0,0);
                    acc10 = __builtin_amdgcn_mfma_f32_16x16x32_f16(A1, Bf[0][kc], acc10, 0,0,0);
                    acc11 = __builtin_amdgcn_mfma_f32_16x16x32_f16(A1, Bf[1][kc], acc11, 0,0,0);
                }
            } else if (mode == 1) {
                const float* a0 = s32 + (size_t)mrow0*1024 + kp + l4*8;
                const float* a1 = s32 + (size_t)mrow1*1024 + kp + l4*8;
#pragma unroll
                for (int kc = 0; kc < 16; kc++) {
                    f16x8 A0 = cvt8(*(const float4*)(a0 + kc*32), *(const float4*)(a0 + kc*32 + 4));
                    f16x8 A1 = cvt8(*(const float4*)(a1 + kc*32), *(const float4*)(a1 + kc*32 + 4));
                    acc00 = __builtin_amdgcn_mfma_f32_16x16x32_f16(A0, Bf[0][kc], acc00, 0,0,0);
                    acc01 = __builtin_amdgcn_mfma_f32_16x16x32_f16(A0, Bf[1][kc], acc01, 0,0,0);
                    acc10 = __builtin_amdgcn_mfma_f32_16x16x32_f16(A1, Bf[0][kc], acc10, 0,0,0);
                    acc11 = __builtin_amdgcn_mfma_f32_16x16x32_f16(A1, Bf[1][kc], acc11, 0,0,0);
                }
            } else {
                f16x8 A1s;
#pragma unroll
                for (int e = 0; e < 8; e++) A1s[e] = (f16)1.f;
#pragma unroll
                for (int kc = 0; kc < 16; kc++) {
                    acc00 = __builtin_amdgcn_mfma_f32_16x16x32_f16(A1s, Bf[0][kc], acc00, 0,0,0);
                    acc01 = __builtin_amdgcn_mfma_f32_16x16x32_f16(A1s, Bf[1][kc], acc01, 0,0,0);
                    acc10 = __builtin_amdgcn_mfma_f32_16x16x32_f16(A1s, Bf[0][kc], acc10, 0,0,0);
                    acc11 = __builtin_amdgcn_mfma_f32_16x16x32_f16(A1s, Bf[1][kc], acc11, 0,0,0);
                }
            }

            // partials -> LDS (tile-lane-major, b128), 4-way reduce (verbatim)
            {
                const int base = kq*2048 + lane*4;
                *(f32x4*)&lds_part[base + (((mh<<1)+0)*2 + 0)*256] = acc00;
                *(f32x4*)&lds_part[base + (((mh<<1)+0)*2 + 1)*256] = acc01;
                *(f32x4*)&lds_part[base + (((mh<<1)+1)*2 + 0)*256] = acc10;
                *(f32x4*)&lds_part[base + (((mh<<1)+1)*2 + 1)*256] = acc11;
            }
            __syncthreads();
            {
                f32x4 sum = *(const f32x4*)&lds_part[tid*4];
                sum += *(const f32x4*)&lds_part[2048 + tid*4];
                sum += *(const f32x4*)&lds_part[4096 + tid*4];
                sum += *(const f32x4*)&lds_part[6144 + tid*4];
                *(f32x4*)&lds_out[tid*4] = sum;
            }
            __syncthreads();
            // elementwise LSTM cell for (bm, j)
            {
                float gi = lds_out[(tI+0)*256 + (li +     u)*4 + rr] + bi;
                float gf = lds_out[(tI+0)*256 + (li + 8 + u)*4 + rr] + bff;
                float gg = lds_out[(tI+1)*256 + (li +     u)*4 + rr] + bgg;
                float go = lds_out[(tI+1)*256 + (li + 8 + u)*4 + rr] + boo;
                float iv = sigm(gi), fv = sigm(gf), gv = tanh_f(gg), ov = sigm(go);
                c = fv*c + iv*gv;
                float h = ov * tanh_f(c);
                if (layer == 0) {
                    // block-major: slab s+1, region (bid&127), element tid — wave-coalesced
                    f16 hv = (f16)h;
                    short hs = __builtin_bit_cast(short, hv);
                    __hip_atomic_store((short*)(h1 + (size_t)(s+1)*BH + (size_t)(bid&127)*512 + tid), hs,
                                       __ATOMIC_RELAXED, __HIP_MEMORY_SCOPE_AGENT);
                } else {
                    __hip_atomic_store(out + (size_t)(s-1)*BH + bm*1024 + j, h,
                                       __ATOMIC_RELAXED, __HIP_MEMORY_SCOPE_AGENT);
                }
            }
        }

        // ---- publish step s: drain write-through stores, then flag store ----
        __builtin_amdgcn_s_waitcnt(0);   // vmcnt(0): stores globally visible
        __syncthreads();
        if (tid == 0)
            flag_store(flags + bid, (unsigned)(s + 1));
    }
}

extern "C" void kernel_launch(void* const* d_in, const int* in_sizes, int n_in,
                              void* d_out, int out_size, void* d_ws, size_t ws_size,
                              hipStream_t stream) {
    const float* x    = (const float*)d_in[0];
    const float* wih0 = (const float*)d_in[1];
    const float* whh0 = (const float*)d_in[2];
    const float* b0   = (const float*)d_in[3];
    const float* wih1 = (const float*)d_in[4];
    const float* whh1 = (const float*)d_in[5];
    const float* b1   = (const float*)d_in[6];
    float* out = (float*)d_out;

    char* ws = (char*)d_ws;
    unsigned* flags = (unsigned*)(ws + OFF_FLAG);
    f16* h1         = (f16*)(ws + OFF_H1);

    prep_kernel<<<256, 256, 0, stream>>>(h1, flags);
    lstm_kernel<<<NBLK, 512, 0, stream>>>(x, wih0, whh0, b0, wih1, whh1, b1,
                                          h1, out, flags);
}